// Round 18
// baseline (225.772 us; speedup 1.0000x reference)
//
#include <hip/hip_runtime.h>
#include <hip/hip_bf16.h>
#include <stdint.h>

// out[m][n] = (sum_k x[m][k] * W[n][k]) * scale[n]
// M=8192 (B*S), N=4096 (D_OUT), K=4096 (D_IN)
// x fp32, W int32 (harness materializes integer inputs as int32), scale fp32.
// INT8 path: W exact int8; x per-row symmetric int8 (sx=amax/127).
// GEMM via mfma_i32_16x16x64_i8. Dequant: out = acc * sx[row] * scale[col].
// *** ZERO LDS, ZERO BARRIERS ***: BOTH operands pre-packed in MFMA fragment
// order and streamed global->VGPR fully coalesced (1 KB/wave/instr), double
// buffered in registers, 2-tile prefetch distance. Compiler handles all
// dependency waits (register-tracked). Rationale: r14/r15/r17 proved the
// ~1300 cy/tile stall is the barrier-synchronized LDS handoff itself, not
// LDS bandwidth (r17: halved LDS traffic, zero change). qx = 32 MB, qw =
// 16 MB -> both L3-resident; same-XCD blocks share the bm A-panel (T1).
//  A-pack: qa[((t*512 + gm)*64 + lane)*16 + b] = i8(x_q[gm*16 + (lane&15)]
//          [t*64 + (lane>>4)*16 + b]),  gm = global 16-row m-group.
//  B-pack: qw[((t*256 + gn)*64 + lane)*16 + b] likewise (r17, verified).

#define M_TOT 8192
#define N_TOT 4096
#define K_TOT 4096
#define NT 64            // k-tiles of 64

typedef int intx4 __attribute__((ext_vector_type(4)));

// ---- x quantization + A-fragment pack: one block per 16-row m-group ----
__global__ void quant_x_kernel(const float* __restrict__ x,
                               char* __restrict__ qa,     // fragment-packed A
                               float* __restrict__ xs) {  // [M] dequant scale
  const int g = blockIdx.x;        // m-group, 0..511
  const int tid = threadIdx.x;     // 256 threads
  __shared__ float part[16][17];
  __shared__ float inv16[16];
  const int r = tid & 15, q = tid >> 4;   // row-in-group, k-quarter
  // phase 1: per-row amax (each thread streams 256 floats of row r)
  const float4* xr = (const float4*)(x + ((size_t)g * 16 + r) * K_TOT + q * 256);
  float am = 0.f;
#pragma unroll 8
  for (int j = 0; j < 64; ++j) {
    float4 v = xr[j];
    am = fmaxf(am, fmaxf(fmaxf(fabsf(v.x), fabsf(v.y)),
                         fmaxf(fabsf(v.z), fabsf(v.w))));
  }
  part[r][q] = am;
  __syncthreads();
  if (tid < 16) {
    float m = 0.f;
#pragma unroll
    for (int j = 0; j < 16; ++j) m = fmaxf(m, part[tid][j]);
    xs[g * 16 + tid] = m * (1.0f / 127.0f);
    inv16[tid] = 127.0f / fmaxf(m, 1e-30f);
  }
  __syncthreads();
  // phase 2: write 16 fragments per thread (coalesced 16B stores; reads L2-hot)
#pragma unroll
  for (int j = 0; j < 16; ++j) {
    const int f = tid + 256 * j;          // fragment id 0..4095
    const int t = f >> 6, lane = f & 63;
    const int row16 = lane & 15, c = lane >> 4;
    const float4* s = (const float4*)(x + ((size_t)g * 16 + row16) * K_TOT +
                                      t * 64 + c * 16);
    const float iv = inv16[row16];
    int4 o;
    int* op = (int*)&o;
#pragma unroll
    for (int w = 0; w < 4; ++w) {
      float4 v = s[w];
      int b0 = __float2int_rn(v.x * iv);
      int b1 = __float2int_rn(v.y * iv);
      int b2 = __float2int_rn(v.z * iv);
      int b3 = __float2int_rn(v.w * iv);
      op[w] = (b0 & 255) | ((b1 & 255) << 8) | ((b2 & 255) << 16) | (b3 << 24);
    }
    *(int4*)(qa + (((size_t)t * 512 + g) * 64 + lane) * 16) = o;
  }
}

__device__ __forceinline__ int pack4(int4 r) {
  return (r.x & 255) | ((r.y & 255) << 8) | ((r.z & 255) << 16) | (r.w << 24);
}

// ---- W repack: int32 -> i8 in MFMA B-fragment order (r17, verified) ----
__global__ void pack_w_kernel(const int* __restrict__ in, int4* __restrict__ out) {
  const int gid = blockIdx.x * 256 + threadIdx.x;  // one 16B fragment each
  const int lane = gid & 63;
  const int g = (gid >> 6) & 255;   // n-group (16 rows)
  const int t = gid >> 14;          // k-tile
  const int row = g * 16 + (lane & 15);
  const int kb = t * 64 + (lane >> 4) * 16;
  const int4* src = (const int4*)(in + (size_t)row * K_TOT + kb);
  int4 r0 = src[0], r1 = src[1], r2 = src[2], r3 = src[3];
  int4 o;
  o.x = pack4(r0); o.y = pack4(r1); o.z = pack4(r2); o.w = pack4(r3);
  out[gid] = o;
}

#define SGB(MASK, N) __builtin_amdgcn_sched_group_barrier(MASK, N, 0)
// LLVM SchedGroupMask: MFMA=0x8, VMEM=0x10

// ---- main GEMM: i8, 256x256 tile, 8 waves (2x4), no LDS, no barriers ----
__global__ __launch_bounds__(512, 2)
void wq_gemm_kernel(const char* __restrict__ Ap,    // fragment-packed x i8
                    const char* __restrict__ Bp,    // fragment-packed W i8
                    const float* __restrict__ XS,   // [M] x dequant scale
                    const float* __restrict__ scale,// [N]
                    float* __restrict__ C) {        // [M][N]
  // XCD-aware block swizzle (nwg=512, divisible by 8): same-XCD blocks share
  // the bm A-panel in their L2.
  const int nb = gridDim.x;
  const int swz = (blockIdx.x & 7) * (nb >> 3) + (blockIdx.x >> 3);
  const int bm = swz >> 4;        // M/256 = 32
  const int bn = swz & 15;        // N/256 = 16

  const int tid = threadIdx.x;
  const int wave = tid >> 6, lane = tid & 63;
  const int wr = wave >> 2, wc = wave & 3;   // 2 x 4 wave grid
  const int l15 = lane & 15, lk = lane >> 4;

  // per-wave fragment stream bases (consecutive lanes -> consecutive 16B)
  const char* aP = Ap + ((size_t)((bm * 16 + wr * 8) * 64 + lane) << 4);
  const char* bP = Bp + ((size_t)((bn * 16 + wc * 4) * 64 + lane) << 4);
  // af[mi] @ tile T: aP + T*524288 + mi*1024   (A t-stride = 512 groups*1KB)
  // bf[ni] @ tile T: bP + T*262144 + ni*1024   (B t-stride = 256 groups*1KB)

  intx4 acc[8][4] = {};
  intx4 afA[8], afB[8], bfA[4], bfB[4];

#define LDG_A(AF, T)                                                      \
  _Pragma("unroll") for (int mi = 0; mi < 8; ++mi)                        \
      AF[mi] = *(const intx4*)(aP + (size_t)(T) * 524288 + mi * 1024);
#define LDG_B(BF, T)                                                      \
  _Pragma("unroll") for (int ni = 0; ni < 4; ++ni)                        \
      BF[ni] = *(const intx4*)(bP + (size_t)(T) * 262144 + ni * 1024);

  // body: 32 MFMA consuming (AF,BF); per mi-group, after its 4 MFMAs issue,
  // reload AF[mi] from tile T2 (WAR safe: load writes after MFMA issue; the
  // compiler orders and inserts the counted vmcnt before next use). B
  // reloads at the end (bf used by every mi-group). SGB interleaves
  // {4 MFMA, 1 VMEM} x8 + 4 VMEM so loads issue early under compute.
#define GBODY(AF, BF, T2, PF)                                             \
  do {                                                                    \
    _Pragma("unroll") for (int mi = 0; mi < 8; ++mi) {                    \
      _Pragma("unroll") for (int ni = 0; ni < 4; ++ni)                    \
          acc[mi][ni] = __builtin_amdgcn_mfma_i32_16x16x64_i8(            \
              AF[mi], BF[ni], acc[mi][ni], 0, 0, 0);                      \
      if (PF) AF[mi] =                                                    \
          *(const intx4*)(aP + (size_t)(T2) * 524288 + mi * 1024);        \
    }                                                                     \
    if (PF) { LDG_B(BF, T2); }                                            \
    _Pragma("unroll") for (int s = 0; s < 8; ++s) {                       \
      SGB(0x8, 4); SGB(0x10, 1);                                          \
    }                                                                     \
    SGB(0x10, 4);                                                         \
    __builtin_amdgcn_sched_barrier(0);                                    \
  } while (0)

  // ---- prologue: tiles 0,1 into the two register buffers ----
  LDG_A(afA, 0); LDG_B(bfA, 0);
  LDG_A(afB, 1); LDG_B(bfB, 1);

  // ---- main loop: 2-unrolled, prefetch distance 2 ----
  for (int t = 0; t + 3 < NT; t += 2) {
    GBODY(afA, bfA, t + 2, 1);
    GBODY(afB, bfB, t + 3, 1);
  }
  // tail: tiles NT-2, NT-1, no prefetch
  GBODY(afA, bfA, 0, 0);
  GBODY(afB, bfB, 0, 0);
#undef GBODY

  // ---- epilogue: D mapping col=lane&15, row=(lane>>4)*4+e; dequant.
  // row = bm*256 + wr*128 + mi*16 + lk*4 + e (A-pack group mapping);
  // col = bn*256 + wc*64 + ni*16 + l15 (B-pack group mapping, r17-verified).
  const size_t crow0 = (size_t)bm * 256 + wr * 128 + (lk << 2);
  const int ccol0 = bn * 256 + wc * 64 + l15;
  float sc4[4];
#pragma unroll
  for (int ni = 0; ni < 4; ++ni) sc4[ni] = scale[ccol0 + ni * 16];
#pragma unroll
  for (int mi = 0; mi < 8; ++mi) {
#pragma unroll
    for (int e = 0; e < 4; ++e) {
      const size_t r = crow0 + (size_t)mi * 16 + e;
      const float xr = XS[r];
#pragma unroll
      for (int ni = 0; ni < 4; ++ni)
        C[r * N_TOT + ccol0 + ni * 16] = (float)acc[mi][ni][e] * xr * sc4[ni];
    }
  }
}

// ---- fallback if workspace too small (insurance; slow but correct) ----
__global__ void naive_kernel(const float* __restrict__ x,
                             const int* __restrict__ w,
                             const float* __restrict__ s,
                             float* __restrict__ out) {
  int m = blockIdx.y;
  int n = blockIdx.x * 256 + threadIdx.x;
  const float* xr = x + (size_t)m * K_TOT;
  const int* wr = w + (size_t)n * K_TOT;
  float acc = 0.f;
  for (int k = 0; k < K_TOT; ++k) acc += xr[k] * (float)wr[k];
  out[(size_t)m * N_TOT + n] = acc * s[n];
}

extern "C" void kernel_launch(void* const* d_in, const int* in_sizes, int n_in,
                              void* d_out, int out_size, void* d_ws, size_t ws_size,
                              hipStream_t stream) {
  const float* x = (const float*)d_in[0];
  const int* w = (const int*)d_in[1];
  const float* scale = (const float*)d_in[2];
  float* out = (float*)d_out;

  const size_t x_elems = (size_t)M_TOT * K_TOT;   // i8 bytes
  const size_t w_elems = (size_t)N_TOT * K_TOT;   // i8 bytes
  const size_t need = x_elems + w_elems + M_TOT * sizeof(float);

  if (ws_size < need) {
    dim3 g(N_TOT / 256, M_TOT);
    naive_kernel<<<g, 256, 0, stream>>>(x, w, scale, out);
    return;
  }

  char* qa = (char*)d_ws;
  char* qw = qa + x_elems;
  float* xs = (float*)(qw + w_elems);

  quant_x_kernel<<<M_TOT / 16, 256, 0, stream>>>(x, qa, xs);
  pack_w_kernel<<<(int)(w_elems / 16 / 256), 256, 0, stream>>>(
      (const int*)w, (int4*)qw);

  wq_gemm_kernel<<<(M_TOT / 256) * (N_TOT / 256), 512, 0, stream>>>(
      qa, qw, xs, scale, out);
}

// Round 19
// 203.956 us; speedup vs baseline: 1.1070x; 1.1070x over previous
//
#include <hip/hip_runtime.h>
#include <hip/hip_bf16.h>
#include <stdint.h>

// out[m][n] = (sum_k x[m][k] * W[n][k]) * scale[n]
// M=8192 (B*S), N=4096 (D_OUT), K=4096 (D_IN)
// x fp32, W int32 (harness materializes integer inputs as int32), scale fp32.
// INT8 path: W exact int8; x per-row symmetric int8 (sx=amax/127).
// GEMM via mfma_i32_16x16x64_i8. Dequant: out = acc * sx[row] * scale[col].
// Structure: r17 skeleton (A via LDS, B fragment-packed global->reg) with
// *** ONE BARRIER PER TWO K-TILES ***: 6-buffer A ring (96 KiB), period =
// {stage A(T+4),A(T+5); reads+MFMA tile T; reload B(T+2); reads+MFMA tile
// T+1; reload B(T+3); vmcnt(12)+lgkmcnt(0)+BAR}. vmcnt(12) keeps this
// period's 4 A-stages + 8 B-loads in flight (never drains to 0 mid-loop);
// older stages certified. lgkmcnt(0) closes the read-vs-next-period-stage
// WAR (next period stages exactly the bufs read this period).
// Rationale: r15/r17/r18 isolated a ~1250 cy/tile per-barrier sync cost that
// traffic cuts don't touch and barrier-removal can't afford (r18 cache-bound).
// Halve barriers/tile -> halve overhead/tile.
// Conflict-free 64B-row swizzle on A (0 conflicts, r9-r17). T1 XCD swizzle.

#define M_TOT 8192
#define N_TOT 4096
#define K_TOT 4096
#define BM 256
#define BN 256
#define BK 64
#define NT (K_TOT / BK)   // 64 k-tiles

typedef int intx4 __attribute__((ext_vector_type(4)));

// ---- x quantization: one block per row (row-major qx, r8-r15 verified) ----
__global__ void quant_x_kernel(const float* __restrict__ x,
                               int* __restrict__ q,       // packed i8, 4/int
                               float* __restrict__ xs) {  // [M] dequant scale
  const int row = blockIdx.x;
  const int tid = threadIdx.x;
  const float4* xr = (const float4*)(x + (size_t)row * K_TOT);
  float4 v[4];
#pragma unroll
  for (int j = 0; j < 4; ++j) v[j] = xr[tid + 256 * j];
  float am = 0.f;
#pragma unroll
  for (int j = 0; j < 4; ++j) {
    am = fmaxf(am, fmaxf(fmaxf(fabsf(v[j].x), fabsf(v[j].y)),
                         fmaxf(fabsf(v[j].z), fabsf(v[j].w))));
  }
#pragma unroll
  for (int off = 32; off >= 1; off >>= 1)
    am = fmaxf(am, __shfl_xor(am, off));
  __shared__ float wmax[4];
  if ((tid & 63) == 0) wmax[tid >> 6] = am;
  __syncthreads();
  am = fmaxf(fmaxf(wmax[0], wmax[1]), fmaxf(wmax[2], wmax[3]));
  const float inv = 127.0f / fmaxf(am, 1e-30f);
  int* qo = q + (size_t)row * (K_TOT / 4);
#pragma unroll
  for (int j = 0; j < 4; ++j) {
    int b0 = __float2int_rn(v[j].x * inv);
    int b1 = __float2int_rn(v[j].y * inv);
    int b2 = __float2int_rn(v[j].z * inv);
    int b3 = __float2int_rn(v[j].w * inv);
    qo[tid + 256 * j] =
        (b0 & 255) | ((b1 & 255) << 8) | ((b2 & 255) << 16) | (b3 << 24);
  }
  if (tid == 0) xs[row] = am * (1.0f / 127.0f);
}

__device__ __forceinline__ int pack4(int4 r) {
  return (r.x & 255) | ((r.y & 255) << 8) | ((r.z & 255) << 16) | (r.w << 24);
}

// ---- W repack: int32 -> i8 in MFMA B-fragment order (r17, verified) ----
__global__ void pack_w_kernel(const int* __restrict__ in, int4* __restrict__ out) {
  const int gid = blockIdx.x * 256 + threadIdx.x;  // one 16B fragment each
  const int lane = gid & 63;
  const int g = (gid >> 6) & 255;   // n-group (16 rows)
  const int t = gid >> 14;          // k-tile
  const int row = g * 16 + (lane & 15);
  const int kb = t * 64 + (lane >> 4) * 16;
  const int4* src = (const int4*)(in + (size_t)row * K_TOT + kb);
  int4 r0 = src[0], r1 = src[1], r2 = src[2], r3 = src[3];
  int4 o;
  o.x = pack4(r0); o.y = pack4(r1); o.z = pack4(r2); o.w = pack4(r3);
  out[gid] = o;
}

// ---- async global->LDS (16B per lane, wave-uniform dest + lane*16) ----
__device__ __forceinline__ void gload_lds16(const void* g, const void* l) {
  const __attribute__((address_space(1))) void* gp =
      reinterpret_cast<const __attribute__((address_space(1))) void*>(
          reinterpret_cast<uintptr_t>(g));
  __attribute__((address_space(3))) void* lp =
      reinterpret_cast<__attribute__((address_space(3))) void*>(
          (uint32_t)reinterpret_cast<uintptr_t>(l));
  __builtin_amdgcn_global_load_lds(gp, lp, 16, 0, 0);
}

#define BAR() __builtin_amdgcn_s_barrier()
#define VMCNT(N) asm volatile("s_waitcnt vmcnt(" #N ")" ::: "memory")
#define LGKM0() asm volatile("s_waitcnt lgkmcnt(0)" ::: "memory")
#define SGB(MASK, N) __builtin_amdgcn_sched_group_barrier(MASK, N, 0)
// LLVM SchedGroupMask: MFMA=0x8, VMEM=0x10, DS_READ=0x100

// ---- main GEMM: i8, 256x256 tile, 8 waves (2x4), 2 tiles per barrier ----
__global__ __launch_bounds__(512, 2)
void wq_gemm_kernel(const char* __restrict__ A,     // [M][K] i8 (quantized x)
                    const char* __restrict__ Bp,    // fragment-packed W i8
                    const float* __restrict__ XS,   // [M] x dequant scale
                    const float* __restrict__ scale,// [N]
                    float* __restrict__ C) {        // [M][N]
  // A only: 6-buffer ring, [buf][256 rows][64 B] = 6 x 16 KiB = 96 KiB.
  __shared__ __align__(16) char As[6][BM * BK];

  // XCD-aware block swizzle (nwg=512, divisible by 8)
  const int nb = gridDim.x;
  const int swz = (blockIdx.x & 7) * (nb >> 3) + (blockIdx.x >> 3);
  const int bm = swz >> 4;        // M/BM = 32
  const int bn = swz & 15;        // N/BN = 16

  const int tid = threadIdx.x;
  const int wave = tid >> 6, lane = tid & 63;
  const int wr = wave >> 2, wc = wave & 3;   // 2 x 4 wave grid
  const int l15 = lane & 15, lk = lane >> 4;
  const int wr16l = wr * 16 + l15;
  // Conflict-free 64B-row swizzle on A (HW-verified 0 conflicts, r9-r17):
  // phys chunk = lk ^ ((row>>1)&3); frag rows have row&15 == l15.
  const int rchunk = (lk ^ ((l15 >> 1) & 3)) << 4;  // bytes

  intx4 acc[8][4] = {};
  intx4 af[8], bfA[4], bfB[4];

  // A staging: one gload = 512 threads x 16B = 128 rows x 64B; 2 per tile.
  // LDS dest linear; global source chunk pre-swizzled (involution).
  const int srow = tid >> 2;                     // 0..127
  const int sc = (tid & 3) ^ ((tid >> 3) & 3);   // source 16B chunk
  const char* gA = A + (size_t)(bm * BM + srow) * K_TOT + sc * 16;
  // B fragment stream base: group g = bn*16 + wc*4 + ni; addr =
  // ((t*256 + g)*64 + lane)*16. Consecutive lanes -> consecutive 16B.
  const char* gBp = Bp + ((size_t)((bn * 16 + wc * 4) * 64 + lane) << 4);

#define STAGE_A2(P, KT)                                                   \
  do {                                                                    \
    gload_lds16(gA + (size_t)(KT) * BK, As[P] + wave * 1024);             \
    gload_lds16(gA + (size_t)128 * K_TOT + (size_t)(KT) * BK,             \
                As[P] + 8192 + wave * 1024);                              \
  } while (0)

#define DS16(BASE, ROW)                                                   \
  *(const intx4*)((BASE) + (ROW) * BK + rchunk)

  // All 8 m-fragments of one tile (rows mi*32 + wr*16 + l15).
#define LD_AF(P)                                                          \
  _Pragma("unroll") for (int mi = 0; mi < 8; ++mi)                        \
      af[mi] = DS16(As[P], mi * 32 + wr16l);

  // B fragment loads: 4 x b128, fully coalesced (1 KB/wave/instr), L2-hot.
#define LDG_B(BF, T)                                                      \
  _Pragma("unroll") for (int ni = 0; ni < 4; ++ni)                        \
      BF[ni] = *(const intx4*)(gBp + (size_t)(T) * 262144 + ni * 1024);

  // Full tile: 8 mi x 4 ni = 32 MFMA (K=64 each).
#define MFMA32(BF)                                                        \
  _Pragma("unroll") for (int mi2 = 0; mi2 < 8; ++mi2)                     \
  _Pragma("unroll") for (int ni2 = 0; ni2 < 4; ++ni2)                     \
      acc[mi2][ni2] = __builtin_amdgcn_mfma_i32_16x16x64_i8(              \
          af[mi2], bf ## BF[ni2], acc[mi2][ni2], 0, 0, 0);

  // Period interleave hint: 64 MFMA + 16 DS_READ + up to 12 VMEM.
#define SGB_P()                                                           \
  _Pragma("unroll") for (int s = 0; s < 8; ++s) {                         \
    SGB(0x8, 4); SGB(0x100, 1); SGB(0x8, 4); SGB(0x100, 1); SGB(0x10, 1); \
  }                                                                       \
  SGB(0x10, 4);

  // PERIOD: tiles T (buf P0), T+1 (buf P1); stage T+4 -> S0, T+5 -> S1.
  // End-of-period vmcnt(VMN) certifies last period's stages; this period's
  // 4 stages + 8 B-loads stay in flight. lgkmcnt(0): my ds_reads returned
  // before the barrier releases next period's stagers into these bufs.
#define PERIOD(P0, P1, S0, S1, T, STG, LDB, VMN, SYNC)                    \
  do {                                                                    \
    if (STG) { STAGE_A2(S0, (T) + 4); STAGE_A2(S1, (T) + 5); }            \
    LD_AF(P0);                                                            \
    MFMA32(A);                                                            \
    if (LDB) { LDG_B(bfA, (T) + 2); }                                     \
    LD_AF(P1);                                                            \
    MFMA32(B);                                                            \
    if (LDB) { LDG_B(bfB, (T) + 3); }                                     \
    SGB_P();                                                              \
    if (SYNC) {                                                           \
      VMCNT(VMN);                                                         \
      LGKM0();                                                            \
      BAR();                                                              \
      __builtin_amdgcn_sched_barrier(0);                                  \
    }                                                                     \
  } while (0)

  // ---- prologue: stage A(0..3), load B(0),B(1); certify A(0),A(1) ----
  STAGE_A2(0, 0); STAGE_A2(1, 1); STAGE_A2(2, 2); STAGE_A2(3, 3);
  LDG_B(bfA, 0); LDG_B(bfB, 1);
  VMCNT(12);   // A(0),A(1) drained; A(2),A(3) + B(0),B(1) in flight
  BAR();

  // ---- main loop: 3 periods (6 tiles) per iteration; t = 0..48 ----
  for (int t = 0; t < 54; t += 6) {
    PERIOD(0, 1, 4, 5, t,     1, 1, 12, 1);
    PERIOD(2, 3, 0, 1, t + 2, 1, 1, 12, 1);
    PERIOD(4, 5, 2, 3, t + 4, 1, 1, 12, 1);
  }
  // tail: periods 54,56,58 still stage (58+5=63); 60 no stage (vmcnt(8)
  // leaves only B(62),B(63)); 62 final, no sync.
  PERIOD(0, 1, 4, 5, 54, 1, 1, 12, 1);
  PERIOD(2, 3, 0, 1, 56, 1, 1, 12, 1);
  PERIOD(4, 5, 2, 3, 58, 1, 1, 12, 1);
  PERIOD(0, 1, 4, 5, 60, 0, 1, 8, 1);
  PERIOD(2, 3, 0, 1, 62, 0, 0, 0, 0);
#undef PERIOD

  // ---- epilogue: D mapping col=lane&15, row=(lane>>4)*4+e; dequant.
  // row = bm*256 + mi*32 + wr*16 + lk*4 + e; col = bn*256 + wc*64 + ni*16
  // + l15 (B-pack group mapping, r17-verified).
  const size_t crow0 = (size_t)bm * BM + wr * 16 + (lk << 2);
  const int ccol0 = bn * BN + wc * 64 + l15;
  float sc4[4];
#pragma unroll
  for (int ni = 0; ni < 4; ++ni) sc4[ni] = scale[ccol0 + ni * 16];
#pragma unroll
  for (int mi = 0; mi < 8; ++mi) {
#pragma unroll
    for (int e = 0; e < 4; ++e) {
      const size_t r = crow0 + (size_t)mi * 32 + e;
      const float xr = XS[r];
#pragma unroll
      for (int ni = 0; ni < 4; ++ni)
        C[r * N_TOT + ccol0 + ni * 16] = (float)acc[mi][ni][e] * xr * sc4[ni];
    }
  }
}

// ---- fallback if workspace too small (insurance; slow but correct) ----
__global__ void naive_kernel(const float* __restrict__ x,
                             const int* __restrict__ w,
                             const float* __restrict__ s,
                             float* __restrict__ out) {
  int m = blockIdx.y;
  int n = blockIdx.x * 256 + threadIdx.x;
  const float* xr = x + (size_t)m * K_TOT;
  const int* wr = w + (size_t)n * K_TOT;
  float acc = 0.f;
  for (int k = 0; k < K_TOT; ++k) acc += xr[k] * (float)wr[k];
  out[(size_t)m * N_TOT + n] = acc * s[n];
}

extern "C" void kernel_launch(void* const* d_in, const int* in_sizes, int n_in,
                              void* d_out, int out_size, void* d_ws, size_t ws_size,
                              hipStream_t stream) {
  const float* x = (const float*)d_in[0];
  const int* w = (const int*)d_in[1];
  const float* scale = (const float*)d_in[2];
  float* out = (float*)d_out;

  const size_t x_elems = (size_t)M_TOT * K_TOT;   // i8 bytes
  const size_t w_elems = (size_t)N_TOT * K_TOT;   // i8 bytes
  const size_t need = x_elems + w_elems + M_TOT * sizeof(float);

  if (ws_size < need) {
    dim3 g(N_TOT / 256, M_TOT);
    naive_kernel<<<g, 256, 0, stream>>>(x, w, scale, out);
    return;
  }

  char* qx = (char*)d_ws;
  char* qw = qx + x_elems;
  float* xs = (float*)(qw + w_elems);

  quant_x_kernel<<<M_TOT, 256, 0, stream>>>(x, (int*)qx, xs);
  pack_w_kernel<<<(int)(w_elems / 16 / 256), 256, 0, stream>>>(
      (const int*)w, (int4*)qw);

  wq_gemm_kernel<<<(M_TOT / BM) * (N_TOT / BN), 512, 0, stream>>>(
      qx, qw, xs, scale, out);
}

// Round 20
// 177.250 us; speedup vs baseline: 1.2737x; 1.1507x over previous
//
#include <hip/hip_runtime.h>
#include <hip/hip_bf16.h>
#include <stdint.h>

// out[m][n] = (sum_k x[m][k] * W[n][k]) * scale[n]
// M=8192 (B*S), N=4096 (D_OUT), K=4096 (D_IN)
// x fp32, W int32 (harness materializes integer inputs as int32), scale fp32.
// INT8 path: W exact int8; x per-row symmetric int8 (sx=amax/127).
// GEMM via mfma_i32_16x16x64_i8. Dequant: out = acc * sx[row] * scale[col].
// Structure = r15 verbatim (best measured: GEMM 136.4 us, MfmaUtil 45.7%):
// 256x256 tile, 8 waves 2x4, A+B 4-buffer LDS rotation (128 KiB), stage
// distance 3, cross-tile register prefetch, mid-body vmcnt(8)+lgkmcnt(0)+BAR,
// T19 SGB interleave. Adds this round:
//   (1) T5 setprio(1) around both MFMA clusters (r15 dropped it to isolate
//       SGB; catalog prereq -- phase-split waves -- is now present);
//   (2) quant_x + pack_w fused into ONE launch (independent kernels; saves
//       a launch gap and overlaps their BW).
// Conflict-free 64B-row swizzle (0 conflicts, r9-r15). T1 XCD swizzle.

#define M_TOT 8192
#define N_TOT 4096
#define K_TOT 4096
#define BM 256
#define BN 256
#define BK 64
#define NT (K_TOT / BK)   // 64 k-tiles

typedef int intx4 __attribute__((ext_vector_type(4)));

__device__ __forceinline__ int pack4(int4 r) {
  return (r.x & 255) | ((r.y & 255) << 8) | ((r.z & 255) << 16) | (r.w << 24);
}

// ---- fused pre-pass: blocks [0,8192) quantize x rows; [8192,12288) pack W ----
__global__ void prep_kernel(const float* __restrict__ x,
                            const int* __restrict__ w,
                            int* __restrict__ q,        // packed x i8, 4/int
                            float* __restrict__ xs,     // [M] dequant scale
                            int4* __restrict__ wout) {  // W i8 row-major
  const int tid = threadIdx.x;
  if (blockIdx.x < M_TOT) {
    const int row = blockIdx.x;
    const float4* xr = (const float4*)(x + (size_t)row * K_TOT);
    float4 v[4];
#pragma unroll
    for (int j = 0; j < 4; ++j) v[j] = xr[tid + 256 * j];
    float am = 0.f;
#pragma unroll
    for (int j = 0; j < 4; ++j) {
      am = fmaxf(am, fmaxf(fmaxf(fabsf(v[j].x), fabsf(v[j].y)),
                           fmaxf(fabsf(v[j].z), fabsf(v[j].w))));
    }
#pragma unroll
    for (int off = 32; off >= 1; off >>= 1)
      am = fmaxf(am, __shfl_xor(am, off));
    __shared__ float wmax[4];
    if ((tid & 63) == 0) wmax[tid >> 6] = am;
    __syncthreads();
    am = fmaxf(fmaxf(wmax[0], wmax[1]), fmaxf(wmax[2], wmax[3]));
    const float inv = 127.0f / fmaxf(am, 1e-30f);
    int* qo = q + (size_t)row * (K_TOT / 4);
#pragma unroll
    for (int j = 0; j < 4; ++j) {
      int b0 = __float2int_rn(v[j].x * inv);
      int b1 = __float2int_rn(v[j].y * inv);
      int b2 = __float2int_rn(v[j].z * inv);
      int b3 = __float2int_rn(v[j].w * inv);
      qo[tid + 256 * j] =
          (b0 & 255) | ((b1 & 255) << 8) | ((b2 & 255) << 16) | (b3 << 24);
    }
    if (tid == 0) xs[row] = am * (1.0f / 127.0f);
  } else {
    // W repack int32 -> i8 row-major (exact); 16 ints -> 16 bytes per thread
    const int i = (blockIdx.x - M_TOT) * 256 + tid;
    const int4* in4 = (const int4*)w;
    int4 r0 = in4[4 * i], r1 = in4[4 * i + 1];
    int4 r2 = in4[4 * i + 2], r3 = in4[4 * i + 3];
    int4 o;
    o.x = pack4(r0); o.y = pack4(r1); o.z = pack4(r2); o.w = pack4(r3);
    wout[i] = o;
  }
}

// ---- async global->LDS (16B per lane, wave-uniform dest + lane*16) ----
__device__ __forceinline__ void gload_lds16(const void* g, const void* l) {
  const __attribute__((address_space(1))) void* gp =
      reinterpret_cast<const __attribute__((address_space(1))) void*>(
          reinterpret_cast<uintptr_t>(g));
  __attribute__((address_space(3))) void* lp =
      reinterpret_cast<__attribute__((address_space(3))) void*>(
          (uint32_t)reinterpret_cast<uintptr_t>(l));
  __builtin_amdgcn_global_load_lds(gp, lp, 16, 0, 0);
}

#define BAR() __builtin_amdgcn_s_barrier()
#define VMCNT(N) asm volatile("s_waitcnt vmcnt(" #N ")" ::: "memory")
#define LGKM0() asm volatile("s_waitcnt lgkmcnt(0)" ::: "memory")
#define SGB(MASK, N) __builtin_amdgcn_sched_group_barrier(MASK, N, 0)
// LLVM SchedGroupMask: MFMA=0x8, VMEM=0x10, DS_READ=0x100

// ---- main GEMM: i8, 256x256 tile, 8 waves (2x4), SGB + setprio ----
__global__ __launch_bounds__(512, 2)
void wq_gemm_kernel(const char* __restrict__ A,     // [M][K] i8 (quantized x)
                    const char* __restrict__ B,     // [N][K] i8 (W rows)
                    const float* __restrict__ XS,   // [M] x dequant scale
                    const float* __restrict__ scale,// [N]
                    float* __restrict__ C) {        // [M][N]
  // 4-buffer rotation: [buf][256 rows][64 B] per operand = 4 x 16 KiB x 2.
  __shared__ __align__(16) char As[4][BM * BK];
  __shared__ __align__(16) char Bs[4][BN * BK];

  // XCD-aware block swizzle (nwg=512, divisible by 8)
  const int nb = gridDim.x;
  const int swz = (blockIdx.x & 7) * (nb >> 3) + (blockIdx.x >> 3);
  const int bm = swz >> 4;        // M/BM = 32
  const int bn = swz & 15;        // N/BN = 16

  const int tid = threadIdx.x;
  const int wave = tid >> 6, lane = tid & 63;
  const int wr = wave >> 2, wc = wave & 3;   // 2 x 4 wave grid
  const int l15 = lane & 15, lk = lane >> 4;
  const int wr16l = wr * 16 + l15;
  const int wc16l = wc * 16 + l15;
  // Conflict-free 64B-row swizzle (HW-verified 0 conflicts, r9-r15):
  // phys chunk = lk ^ ((row>>1)&3); frag rows have row&15 == l15.
  const int rchunk = (lk ^ ((l15 >> 1) & 3)) << 4;  // bytes

  intx4 acc[8][4] = {};
  intx4 afL[4], afH[4], bfA[4], bfB[4];

  // Staging: one gload = 512 threads x 16B = 128 rows x 64B; 4 per tile.
  // LDS dest linear; global source chunk pre-swizzled (involution).
  const int srow = tid >> 2;                     // 0..127
  const int sc = (tid & 3) ^ ((tid >> 3) & 3);   // source 16B chunk
  const char* gA = A + (size_t)(bm * BM + srow) * K_TOT + sc * 16;
  const char* gB = B + (size_t)(bn * BN + srow) * K_TOT + sc * 16;

#define STAGE_A(P, J, KT)                                                 \
  gload_lds16(gA + (size_t)(J) * 128 * K_TOT + (size_t)(KT) * BK,         \
              As[P] + (J) * 8192 + wave * 1024)
#define STAGE_B(P, J, KT)                                                 \
  gload_lds16(gB + (size_t)(J) * 128 * K_TOT + (size_t)(KT) * BK,         \
              Bs[P] + (J) * 8192 + wave * 1024)
#define STAGE4(P, KT)                                                     \
  do { STAGE_B(P, 0, KT); STAGE_B(P, 1, KT);                              \
       STAGE_A(P, 0, KT); STAGE_A(P, 1, KT); } while (0)

#define DS16(BASE, ROW)                                                   \
  *(const intx4*)((BASE) + (ROW) * BK + rchunk)

#define LD_AFL(P)                                                         \
  _Pragma("unroll") for (int mi = 0; mi < 4; ++mi)                        \
      afL[mi] = DS16(As[P], mi * 32 + wr16l);
#define LD_A47(P)                                                         \
  _Pragma("unroll") for (int mi = 0; mi < 4; ++mi)                        \
      afH[mi] = DS16(As[P], (mi + 4) * 32 + wr16l);
#define LD_BF(BF, P)                                                      \
  _Pragma("unroll") for (int ni = 0; ni < 4; ++ni)                        \
      BF[ni] = DS16(Bs[P], ni * 64 + wc16l);

  // Half-tile: 4 mi x 4 ni = 16 MFMA (K=64 each), T5 setprio wrapped.
#define MFMA_Q(AF, BF, H)                                                 \
  __builtin_amdgcn_s_setprio(1);                                          \
  _Pragma("unroll") for (int mi2 = 0; mi2 < 4; ++mi2)                     \
  _Pragma("unroll") for (int ni2 = 0; ni2 < 4; ++ni2)                     \
      acc[(H) * 4 + mi2][ni2] = __builtin_amdgcn_mfma_i32_16x16x64_i8(    \
          AF[mi2], bf ## BF[ni2], acc[(H) * 4 + mi2][ni2], 0, 0, 0);      \
  __builtin_amdgcn_s_setprio(0)

  // SGB interleave patterns (counts match region contents exactly).
#define SGB_R1()                                                          \
  _Pragma("unroll") for (int s1 = 0; s1 < 4; ++s1) {                      \
    SGB(0x8, 2); SGB(0x100, 1); SGB(0x8, 2); SGB(0x10, 1);                \
  }
#define SGB_R2()                                                          \
  _Pragma("unroll") for (int s2 = 0; s2 < 8; ++s2) {                      \
    SGB(0x8, 2); SGB(0x100, 1);                                           \
  }

  // body(T): region1 {MFMA0 x16 | A47 reads x4 | stage T+3 x4} interleaved;
  // vmcnt(8)+lgkmcnt(0)+BAR; region2 {next-tile afL/bf reads x8 | MFMA1 x16}
  // interleaved; sched_barrier(0) pins the body boundary.
#define BODY(P, Q, BFC, BFN, T, STG, RA, VMN)                             \
  do {                                                                    \
    MFMA_Q(afL, BFC, 0);                                                  \
    LD_A47(P);                                                            \
    if (STG) { STAGE4(((P) + 3) & 3, (T) + 3); }                          \
    SGB_R1();                                                             \
    VMCNT(VMN);                                                           \
    LGKM0();                                                              \
    BAR();                                                                \
    if (RA) { LD_AFL(Q); LD_BF(bf ## BFN, Q); }                           \
    MFMA_Q(afH, BFC, 1);                                                  \
    SGB_R2();                                                             \
    __builtin_amdgcn_sched_barrier(0);                                    \
  } while (0)

  // ---- prologue: stage t0,t1,t2; certify t0; prefetch tile-0 frags ----
  STAGE4(0, 0);
  STAGE4(1, 1);
  STAGE4(2, 2);
  VMCNT(8);
  BAR();
  LD_AFL(0);
  LD_BF(bfA, 0);

  // ---- main loop: 4-unrolled; tiles t..t+3 all stage (t+6 <= NT-1) ----
  for (int t = 0; t + 7 < NT; t += 4) {
    BODY(0, 1, A, B, t,     1, 1, 8);
    BODY(1, 2, B, A, t + 1, 1, 1, 8);
    BODY(2, 3, A, B, t + 2, 1, 1, 8);
    BODY(3, 0, B, A, t + 3, 1, 1, 8);
  }
  // tail: NT-4 stages NT-1; NT-3/NT-2 no staging; NT-1 plain.
  BODY(0, 1, A, B, NT - 4, 1, 1, 8);
  BODY(1, 2, B, A, NT - 3, 0, 1, 4);
  BODY(2, 3, A, B, NT - 2, 0, 1, 0);
  // tile NT-1 (buf3, bfB): no barrier / stage / read-ahead.
  MFMA_Q(afL, B, 0);
  LD_A47(3);
  MFMA_Q(afH, B, 1);
#undef BODY

  // ---- epilogue: D mapping col=lane&15, row=(lane>>4)*4+e; dequant ----
  const size_t crow0 = (size_t)bm * BM + wr * 16 + (lk << 2);
  const int ccol0 = bn * BN + wc * 16 + l15;
  float sc4[4];
#pragma unroll
  for (int ni = 0; ni < 4; ++ni) sc4[ni] = scale[ccol0 + ni * 64];
#pragma unroll
  for (int mi = 0; mi < 8; ++mi) {
#pragma unroll
    for (int e = 0; e < 4; ++e) {
      const size_t r = crow0 + (size_t)mi * 32 + e;
      const float xr = XS[r];
#pragma unroll
      for (int ni = 0; ni < 4; ++ni)
        C[r * N_TOT + ccol0 + ni * 64] = (float)acc[mi][ni][e] * xr * sc4[ni];
    }
  }
}

// ---- fallback if workspace too small (insurance; slow but correct) ----
__global__ void naive_kernel(const float* __restrict__ x,
                             const int* __restrict__ w,
                             const float* __restrict__ s,
                             float* __restrict__ out) {
  int m = blockIdx.y;
  int n = blockIdx.x * 256 + threadIdx.x;
  const float* xr = x + (size_t)m * K_TOT;
  const int* wr = w + (size_t)n * K_TOT;
  float acc = 0.f;
  for (int k = 0; k < K_TOT; ++k) acc += xr[k] * (float)wr[k];
  out[(size_t)m * N_TOT + n] = acc * s[n];
}

extern "C" void kernel_launch(void* const* d_in, const int* in_sizes, int n_in,
                              void* d_out, int out_size, void* d_ws, size_t ws_size,
                              hipStream_t stream) {
  const float* x = (const float*)d_in[0];
  const int* w = (const int*)d_in[1];
  const float* scale = (const float*)d_in[2];
  float* out = (float*)d_out;

  const size_t x_elems = (size_t)M_TOT * K_TOT;   // i8 bytes
  const size_t w_elems = (size_t)N_TOT * K_TOT;   // i8 bytes
  const size_t need = x_elems + w_elems + M_TOT * sizeof(float);

  if (ws_size < need) {
    dim3 g(N_TOT / 256, M_TOT);
    naive_kernel<<<g, 256, 0, stream>>>(x, w, scale, out);
    return;
  }

  char* qx = (char*)d_ws;
  char* qw = qx + x_elems;
  float* xs = (float*)(qw + w_elems);

  const int prep_grid = M_TOT + (int)(w_elems / 16 / 256);  // 8192 + 4096
  prep_kernel<<<prep_grid, 256, 0, stream>>>(
      x, w, (int*)qx, xs, (int4*)qw);

  wq_gemm_kernel<<<(M_TOT / BM) * (N_TOT / BN), 512, 0, stream>>>(
      qx, qw, xs, scale, out);
}